// Round 6
// baseline (1073.974 us; speedup 1.0000x reference)
//
#include <hip/hip_runtime.h>
#include <hip/hip_bf16.h>

using bf16 = __hip_bfloat16;

#define B_      32
#define HH      56
#define WW      56
#define HIDDEN  96
#define HEADS   3
#define HD      32
#define WS_     7
#define DISP    3
#define NWH     8
#define NWW     8
#define NW      64
#define WS2     49
#define TOKENS  (B_*HH*WW)                        /* 100352 */
#define QKV_ELEMS ((size_t)B_*HEADS*NW*WS2*HD)    /* 9,633,792 */

struct alignas(8) bf16x4 { bf16 a, b, c, d; };

template <typename T> __device__ inline T    encT(float v);
template <> __device__ inline float encT<float>(float v) { return v; }
template <> __device__ inline bf16  encT<bf16>(float v)  { return __float2bfloat16(v); }
template <typename T> __device__ inline float decT(T v);
template <> __device__ inline float decT<float>(float v) { return v; }
template <> __device__ inline float decT<bf16>(bf16 v)   { return __bfloat162float(v); }

// ---------------- Kernel 1: shifted gather + QKV projection + windowing ----
template <typename T>
__global__ __launch_bounds__(256, 2) void qkv_win_kernel(
    const float* __restrict__ x, const float* __restrict__ w_qkv,
    const float* __restrict__ b_qkv,
    T* __restrict__ q, T* __restrict__ k, T* __restrict__ v) {
  __shared__ float xs[64][100];   // 25.6 KB, float4-aligned rows
  __shared__ float wc[32][296];   // 37.9 KB k-chunk
  int tid = threadIdx.x;
  int t0 = blockIdx.x * 64;

  for (int idx = tid; idx < 64 * 96; idx += 256) {
    int tl = idx / 96, ch = idx % 96;
    int tok = t0 + tl;
    int b = tok / (HH * WW); int rem = tok % (HH * WW);
    int hs = rem / WW, wsp = rem % WW;
    int h = (hs + DISP) % HH, w = (wsp + DISP) % WW;   // roll(x, -3, -3)
    xs[tl][ch] = x[((size_t)(b * HH + h) * WW + w) * HIDDEN + ch];
  }

  int colg = tid & 31, tg = tid >> 5;

  size_t base8[8];
#pragma unroll
  for (int t = 0; t < 8; t++) {
    int tok = t0 + tg * 8 + t;
    int b = tok / (HH * WW); int rem = tok % (HH * WW);
    int hs = rem / WW, wsp = rem % WW;
    int wy = hs / WS_, py = hs % WS_, wx = wsp / WS_, px = wsp % WS_;
    int nw = wy * NWW + wx, pos = py * WS_ + px;
    base8[t] = (size_t)b * (HEADS * NW * WS2 * HD) + (size_t)(nw * WS2 + pos) * HD;
  }

  float acc[8][9];
#pragma unroll
  for (int j = 0; j < 9; j++) {
    float bj = b_qkv[colg + 32 * j];
#pragma unroll
    for (int t = 0; t < 8; t++) acc[t][j] = bj;
  }

  for (int kc = 0; kc < 3; kc++) {
    __syncthreads();
    for (int idx = tid; idx < 32 * 288; idx += 256) {
      int r = idx / 288, c = idx - r * 288;
      wc[r][c] = w_qkv[(kc * 32 + r) * 288 + c];
    }
    __syncthreads();

    int kb = kc * 32;
    for (int kk = 0; kk < 32; kk += 4) {
      float4 xv[8];
#pragma unroll
      for (int t = 0; t < 8; t++) xv[t] = *(const float4*)&xs[tg * 8 + t][kb + kk];
#pragma unroll
      for (int j = 0; j < 9; j++) {
        int c = colg + 32 * j;
        float w0 = wc[kk + 0][c], w1 = wc[kk + 1][c];
        float w2 = wc[kk + 2][c], w3 = wc[kk + 3][c];
#pragma unroll
        for (int t = 0; t < 8; t++) {
          acc[t][j] = fmaf(xv[t].x, w0, acc[t][j]);
          acc[t][j] = fmaf(xv[t].y, w1, acc[t][j]);
          acc[t][j] = fmaf(xv[t].z, w2, acc[t][j]);
          acc[t][j] = fmaf(xv[t].w, w3, acc[t][j]);
        }
      }
    }
  }

#pragma unroll
  for (int j = 0; j < 9; j++) {
    T* dst = (j < 3) ? q : ((j < 6) ? k : v);
    int head = j % 3;
    size_t hoff = (size_t)head * (NW * WS2 * HD) + colg;
#pragma unroll
    for (int t = 0; t < 8; t++)
      dst[base8[t] + hoff] = encT<T>(acc[t][j]);
  }
}

// ---------------- Kernel 2: per-window attention --------------------------
__device__ inline void unpack8(float* dst, uint4 u) {
  dst[0] = __uint_as_float(u.x << 16); dst[1] = __uint_as_float(u.x & 0xffff0000u);
  dst[2] = __uint_as_float(u.y << 16); dst[3] = __uint_as_float(u.y & 0xffff0000u);
  dst[4] = __uint_as_float(u.z << 16); dst[5] = __uint_as_float(u.z & 0xffff0000u);
  dst[6] = __uint_as_float(u.w << 16); dst[7] = __uint_as_float(u.w & 0xffff0000u);
}

__global__ __launch_bounds__(256, 4) void attn_kernel(
    const bf16* __restrict__ q, const bf16* __restrict__ k,
    const bf16* __restrict__ v, const float* __restrict__ pos_emb,
    bf16* __restrict__ attn_out) {
  int blk = blockIdx.x;                 // b*192 + head*64 + nw
  int nw = blk % NW; int t2 = blk / NW;
  int head = t2 % HEADS; int b = t2 / HEADS;

  __shared__ float qs[52][36], ks[52][36], vs[52][36];  // [row][d], rows 49-51 zero
  __shared__ float es[49][60];                          // cols 49-51 zero
  __shared__ float pel[169];
  __shared__ float inv[49];
  int tid = threadIdx.x;

  size_t base = ((size_t)(b * HEADS + head) * NW + nw) * (WS2 * HD);
  // 196 x 16B chunks per tensor; uint4 = 8 bf16 per lane -> 1 KB/wave-instr
  if (tid < 196) {
    int row = tid >> 2, d0 = (tid & 3) * 8;
    uint4 uq = ((const uint4*)(q + base))[tid];
    uint4 uk = ((const uint4*)(k + base))[tid];
    uint4 uv = ((const uint4*)(v + base))[tid];
    unpack8(&qs[row][d0], uq);
    unpack8(&ks[row][d0], uk);
    unpack8(&vs[row][d0], uv);
  }
  for (int i = tid; i < 3 * 36; i += 256) {
    int r = 49 + i / 36, c = i % 36;
    qs[r][c] = 0.f; ks[r][c] = 0.f; vs[r][c] = 0.f;
  }
  for (int i = tid; i < 49 * 3; i += 256) es[i / 3][49 + i % 3] = 0.f;
  for (int i = tid; i < 169; i += 256) pel[i] = pos_emb[i];
  __syncthreads();

  const float scale = 0.10206207261596575f;   // 96^-0.5 (HIDDEN, per reference)
  bool masked = (nw >= NW - NWW);             // bottom row of windows only

  // ---- QK^T + bias + mask + exp: 4i x 3j tiles, 221 threads ----
  if (tid < 221) {
    int ig = tid / 17, jg = tid % 17;        // i0 <= 48, j0 <= 48
    int i0 = ig * 4, j0 = jg * 3;
    float acc[4][3] = {};
    for (int kk = 0; kk < 32; kk += 4) {
      float4 kv0 = *(const float4*)&ks[j0 + 0][kk];
      float4 kv1 = *(const float4*)&ks[j0 + 1][kk];
      float4 kv2 = *(const float4*)&ks[j0 + 2][kk];
#pragma unroll
      for (int ii = 0; ii < 4; ii++) {
        float4 qv = *(const float4*)&qs[i0 + ii][kk];
        acc[ii][0] += qv.x * kv0.x + qv.y * kv0.y + qv.z * kv0.z + qv.w * kv0.w;
        acc[ii][1] += qv.x * kv1.x + qv.y * kv1.y + qv.z * kv1.z + qv.w * kv1.w;
        acc[ii][2] += qv.x * kv2.x + qv.y * kv2.y + qv.z * kv2.z + qv.w * kv2.w;
      }
    }
#pragma unroll
    for (int ii = 0; ii < 4; ii++) {
      int i = i0 + ii;
      if (i >= WS2) break;
      int yi = i / WS_, xi = i % WS_;
#pragma unroll
      for (int jj = 0; jj < 3; jj++) {
        int j = j0 + jj;
        if (j >= WS2) continue;
        bool dead = masked && ((i >= 28) != (j >= 28));
        float e = 0.f;
        if (!dead) {
          int yj = j / WS_, xj = j % WS_;
          e = __expf(acc[ii][jj] * scale + pel[(yj - yi + 6) * 13 + (xj - xi + 6)]);
        }
        es[i][j] = e;
      }
    }
  }
  __syncthreads();

  // ---- row sums: 4 lanes per row + shfl combine ----
  if (tid < 196) {
    int i = tid >> 2, qq = tid & 3;
    float s = 0.f;
#pragma unroll
    for (int jj = 0; jj < 13; jj++) s += es[i][qq + 4 * jj];
    s += __shfl_xor(s, 1);
    s += __shfl_xor(s, 2);
    if (qq == 0) inv[i] = 1.0f / s;
  }
  __syncthreads();

  // ---- P*V: 2i x 4d tiles, 200 threads ----
  int wy = nw / NWW, wx = nw % NWW;
  if (tid < 200) {
    int ig = tid >> 3, dg = tid & 7;
    int i0 = ig * 2, d4 = dg * 4;
    float a[2][4] = {};
    for (int j = 0; j < 52; j += 4) {
      float4 e0 = *(const float4*)&es[i0][j];
      float4 e1 = *(const float4*)&es[i0 + 1][j];
#pragma unroll
      for (int jj = 0; jj < 4; jj++) {
        float4 vv = *(const float4*)&vs[j + jj][d4];
        float ee0 = ((const float*)&e0)[jj];
        float ee1 = ((const float*)&e1)[jj];
        a[0][0] = fmaf(ee0, vv.x, a[0][0]); a[0][1] = fmaf(ee0, vv.y, a[0][1]);
        a[0][2] = fmaf(ee0, vv.z, a[0][2]); a[0][3] = fmaf(ee0, vv.w, a[0][3]);
        a[1][0] = fmaf(ee1, vv.x, a[1][0]); a[1][1] = fmaf(ee1, vv.y, a[1][1]);
        a[1][2] = fmaf(ee1, vv.z, a[1][2]); a[1][3] = fmaf(ee1, vv.w, a[1][3]);
      }
    }
#pragma unroll
    for (int ii = 0; ii < 2; ii++) {
      int i = i0 + ii;
      if (i >= WS2) continue;
      float iv = inv[i];
      int py = i / WS_, px = i % WS_;
      int hsp = wy * WS_ + py, wsp = wx * WS_ + px;
      size_t o = ((size_t)(b * HH + hsp) * WW + wsp) * HIDDEN + head * HD + d4;
      bf16x4 st;
      st.a = __float2bfloat16(a[ii][0] * iv);
      st.b = __float2bfloat16(a[ii][1] * iv);
      st.c = __float2bfloat16(a[ii][2] * iv);
      st.d = __float2bfloat16(a[ii][3] * iv);
      *(bf16x4*)&attn_out[o] = st;    // 8B packed store
    }
  }
}

// ---------------- Kernel 3: un-shift gather + output projection -----------
template <typename T>
__global__ __launch_bounds__(256, 2) void proj_kernel(
    const T* __restrict__ attn, const float* __restrict__ w_out,
    const float* __restrict__ b_out, float* __restrict__ out) {
  __shared__ float xs[64][100];
  __shared__ float wc[96][100];   // full weight resident
  int tid = threadIdx.x;
  int t0 = blockIdx.x * 64;

  for (int idx = tid; idx < 64 * 96; idx += 256) {
    int tl = idx / 96, ch = idx % 96;
    int tok = t0 + tl;
    int b = tok / (HH * WW); int rem = tok % (HH * WW);
    int h = rem / WW, w = rem % WW;
    int hs = (h - DISP + HH) % HH, wsp = (w - DISP + WW) % WW;  // roll(out,+3,+3)
    xs[tl][ch] = decT<T>(attn[((size_t)(b * HH + hs) * WW + wsp) * HIDDEN + ch]);
  }
  for (int idx = tid; idx < 96 * 96; idx += 256) {
    int r = idx / 96, c = idx - r * 96;
    wc[r][c] = w_out[idx];
  }
  __syncthreads();

  int colg = tid & 31, tg = tid >> 5;
  float acc[8][3];
#pragma unroll
  for (int j = 0; j < 3; j++) {
    float bj = b_out[colg + 32 * j];
#pragma unroll
    for (int t = 0; t < 8; t++) acc[t][j] = bj;
  }

  for (int kk = 0; kk < 96; kk += 4) {
    float4 xv[8];
#pragma unroll
    for (int t = 0; t < 8; t++) xv[t] = *(const float4*)&xs[tg * 8 + t][kk];
#pragma unroll
    for (int j = 0; j < 3; j++) {
      int c = colg + 32 * j;
      float w0 = wc[kk + 0][c], w1 = wc[kk + 1][c];
      float w2 = wc[kk + 2][c], w3 = wc[kk + 3][c];
#pragma unroll
      for (int t = 0; t < 8; t++) {
        acc[t][j] = fmaf(xv[t].x, w0, acc[t][j]);
        acc[t][j] = fmaf(xv[t].y, w1, acc[t][j]);
        acc[t][j] = fmaf(xv[t].z, w2, acc[t][j]);
        acc[t][j] = fmaf(xv[t].w, w3, acc[t][j]);
      }
    }
  }

#pragma unroll
  for (int j = 0; j < 3; j++)
#pragma unroll
    for (int t = 0; t < 8; t++)
      out[(size_t)(t0 + tg * 8 + t) * HIDDEN + colg + 32 * j] = acc[t][j];
}

extern "C" void kernel_launch(void* const* d_in, const int* in_sizes, int n_in,
                              void* d_out, int out_size, void* d_ws, size_t ws_size,
                              hipStream_t stream) {
  const float* x     = (const float*)d_in[0];
  const float* w_qkv = (const float*)d_in[1];
  const float* b_qkv = (const float*)d_in[2];
  const float* pos   = (const float*)d_in[3];
  const float* w_out = (const float*)d_in[4];
  const float* b_out = (const float*)d_in[5];
  float* out = (float*)d_out;

  bf16* qb = (bf16*)d_ws;
  bf16* kb = qb + QKV_ELEMS;
  bf16* vb = kb + QKV_ELEMS;
  bf16* ab = vb + QKV_ELEMS;
  qkv_win_kernel<bf16><<<TOKENS / 64, 256, 0, stream>>>(x, w_qkv, b_qkv, qb, kb, vb);
  attn_kernel<<<B_ * HEADS * NW, 256, 0, stream>>>(qb, kb, vb, pos, ab);
  proj_kernel<bf16><<<TOKENS / 64, 256, 0, stream>>>(ab, w_out, b_out, out);
}

// Round 7
// 412.159 us; speedup vs baseline: 2.6057x; 2.6057x over previous
//
#include <hip/hip_runtime.h>
#include <hip/hip_bf16.h>

using bf16 = __hip_bfloat16;

#define B_      32
#define HH      56
#define WW      56
#define HIDDEN  96
#define HEADS   3
#define HD      32
#define WS_     7
#define DISP    3
#define NWH     8
#define NWW     8
#define NW      64
#define WS2     49
#define TOKENS  (B_*HH*WW)                        /* 100352 */
#define QKV_ELEMS ((size_t)B_*HEADS*NW*WS2*HD)    /* 9,633,792 */

struct alignas(8) bf16x4 { bf16 a, b, c, d; };

template <typename T> __device__ inline T    encT(float v);
template <> __device__ inline float encT<float>(float v) { return v; }
template <> __device__ inline bf16  encT<bf16>(float v)  { return __float2bfloat16(v); }
template <typename T> __device__ inline float decT(T v);
template <> __device__ inline float decT<float>(float v) { return v; }
template <> __device__ inline float decT<bf16>(bf16 v)   { return __bfloat162float(v); }

// ---------------- Kernel 1: shifted gather + QKV projection + windowing ----
template <typename T>
__global__ __launch_bounds__(256, 2) void qkv_win_kernel(
    const float* __restrict__ x, const float* __restrict__ w_qkv,
    const float* __restrict__ b_qkv,
    T* __restrict__ q, T* __restrict__ k, T* __restrict__ v) {
  __shared__ float xs[64][100];   // 25.6 KB, float4-aligned rows
  __shared__ float wc[32][296];   // 37.9 KB k-chunk
  int tid = threadIdx.x;
  int t0 = blockIdx.x * 64;

  for (int idx = tid; idx < 64 * 96; idx += 256) {
    int tl = idx / 96, ch = idx % 96;
    int tok = t0 + tl;
    int b = tok / (HH * WW); int rem = tok % (HH * WW);
    int hs = rem / WW, wsp = rem % WW;
    int h = (hs + DISP) % HH, w = (wsp + DISP) % WW;   // roll(x, -3, -3)
    xs[tl][ch] = x[((size_t)(b * HH + h) * WW + w) * HIDDEN + ch];
  }

  int colg = tid & 31, tg = tid >> 5;

  size_t base8[8];
#pragma unroll
  for (int t = 0; t < 8; t++) {
    int tok = t0 + tg * 8 + t;
    int b = tok / (HH * WW); int rem = tok % (HH * WW);
    int hs = rem / WW, wsp = rem % WW;
    int wy = hs / WS_, py = hs % WS_, wx = wsp / WS_, px = wsp % WS_;
    int nw = wy * NWW + wx, pos = py * WS_ + px;
    base8[t] = (size_t)b * (HEADS * NW * WS2 * HD) + (size_t)(nw * WS2 + pos) * HD;
  }

  float acc[8][9];
#pragma unroll
  for (int j = 0; j < 9; j++) {
    float bj = b_qkv[colg + 32 * j];
#pragma unroll
    for (int t = 0; t < 8; t++) acc[t][j] = bj;
  }

  for (int kc = 0; kc < 3; kc++) {
    __syncthreads();
    for (int idx = tid; idx < 32 * 288; idx += 256) {
      int r = idx / 288, c = idx - r * 288;
      wc[r][c] = w_qkv[(kc * 32 + r) * 288 + c];
    }
    __syncthreads();

    int kb = kc * 32;
    for (int kk = 0; kk < 32; kk += 4) {
      float4 xv[8];
#pragma unroll
      for (int t = 0; t < 8; t++) xv[t] = *(const float4*)&xs[tg * 8 + t][kb + kk];
#pragma unroll
      for (int j = 0; j < 9; j++) {
        int c = colg + 32 * j;
        float w0 = wc[kk + 0][c], w1 = wc[kk + 1][c];
        float w2 = wc[kk + 2][c], w3 = wc[kk + 3][c];
#pragma unroll
        for (int t = 0; t < 8; t++) {
          acc[t][j] = fmaf(xv[t].x, w0, acc[t][j]);
          acc[t][j] = fmaf(xv[t].y, w1, acc[t][j]);
          acc[t][j] = fmaf(xv[t].z, w2, acc[t][j]);
          acc[t][j] = fmaf(xv[t].w, w3, acc[t][j]);
        }
      }
    }
  }

#pragma unroll
  for (int j = 0; j < 9; j++) {
    T* dst = (j < 3) ? q : ((j < 6) ? k : v);
    int head = j % 3;
    size_t hoff = (size_t)head * (NW * WS2 * HD) + colg;
#pragma unroll
    for (int t = 0; t < 8; t++)
      dst[base8[t] + hoff] = encT<T>(acc[t][j]);
  }
}

// ---------------- Kernel 2: per-window attention --------------------------
__device__ inline void unpack8(float* dst, uint4 u) {
  dst[0] = __uint_as_float(u.x << 16); dst[1] = __uint_as_float(u.x & 0xffff0000u);
  dst[2] = __uint_as_float(u.y << 16); dst[3] = __uint_as_float(u.y & 0xffff0000u);
  dst[4] = __uint_as_float(u.z << 16); dst[5] = __uint_as_float(u.z & 0xffff0000u);
  dst[6] = __uint_as_float(u.w << 16); dst[7] = __uint_as_float(u.w & 0xffff0000u);
}

__global__ __launch_bounds__(256) void attn_kernel(   // NO waves/EU floor: 64-VGPR cap caused spills
    const bf16* __restrict__ q, const bf16* __restrict__ k,
    const bf16* __restrict__ v, const float* __restrict__ pos_emb,
    bf16* __restrict__ attn_out) {
  int blk = blockIdx.x;                 // b*192 + head*64 + nw
  int nw = blk % NW; int t2 = blk / NW;
  int head = t2 % HEADS; int b = t2 / HEADS;

  __shared__ float qs[52][36], ks[52][36], vs[52][36];  // [row][d], rows 49-51 zero
  __shared__ float es[49][60];                          // cols 49-51 zero
  __shared__ float pel[169];
  __shared__ float inv[49];
  int tid = threadIdx.x;

  size_t base = ((size_t)(b * HEADS + head) * NW + nw) * (WS2 * HD);
  // 196 x 16B chunks per tensor; uint4 = 8 bf16 per lane -> 1 KB/wave-instr
  if (tid < 196) {
    int row = tid >> 2, d0 = (tid & 3) * 8;
    uint4 uq = ((const uint4*)(q + base))[tid];
    uint4 uk = ((const uint4*)(k + base))[tid];
    uint4 uv = ((const uint4*)(v + base))[tid];
    unpack8(&qs[row][d0], uq);
    unpack8(&ks[row][d0], uk);
    unpack8(&vs[row][d0], uv);
  }
  for (int i = tid; i < 3 * 36; i += 256) {
    int r = 49 + i / 36, c = i % 36;
    qs[r][c] = 0.f; ks[r][c] = 0.f; vs[r][c] = 0.f;
  }
  for (int i = tid; i < 49 * 3; i += 256) es[i / 3][49 + i % 3] = 0.f;
  for (int i = tid; i < 169; i += 256) pel[i] = pos_emb[i];
  __syncthreads();

  const float scale = 0.10206207261596575f;   // 96^-0.5 (HIDDEN, per reference)
  bool masked = (nw >= NW - NWW);             // bottom row of windows only

  // ---- QK^T + bias + mask + exp: 4i x 3j tiles, 221 threads ----
  if (tid < 221) {
    int ig = tid / 17, jg = tid % 17;        // i0 <= 48, j0 <= 48
    int i0 = ig * 4, j0 = jg * 3;
    float acc[4][3] = {};
    for (int kk = 0; kk < 32; kk += 4) {
      float4 kv0 = *(const float4*)&ks[j0 + 0][kk];
      float4 kv1 = *(const float4*)&ks[j0 + 1][kk];
      float4 kv2 = *(const float4*)&ks[j0 + 2][kk];
#pragma unroll
      for (int ii = 0; ii < 4; ii++) {
        float4 qv = *(const float4*)&qs[i0 + ii][kk];
        acc[ii][0] += qv.x * kv0.x + qv.y * kv0.y + qv.z * kv0.z + qv.w * kv0.w;
        acc[ii][1] += qv.x * kv1.x + qv.y * kv1.y + qv.z * kv1.z + qv.w * kv1.w;
        acc[ii][2] += qv.x * kv2.x + qv.y * kv2.y + qv.z * kv2.z + qv.w * kv2.w;
      }
    }
#pragma unroll
    for (int ii = 0; ii < 4; ii++) {
      int i = i0 + ii;
      if (i >= WS2) break;
      int yi = i / WS_, xi = i % WS_;
#pragma unroll
      for (int jj = 0; jj < 3; jj++) {
        int j = j0 + jj;
        if (j >= WS2) continue;
        bool dead = masked && ((i >= 28) != (j >= 28));
        float e = 0.f;
        if (!dead) {
          int yj = j / WS_, xj = j % WS_;
          e = __expf(acc[ii][jj] * scale + pel[(yj - yi + 6) * 13 + (xj - xi + 6)]);
        }
        es[i][j] = e;
      }
    }
  }
  __syncthreads();

  // ---- row sums: 4 lanes per row + shfl combine ----
  if (tid < 196) {
    int i = tid >> 2, qq = tid & 3;
    float s = 0.f;
#pragma unroll
    for (int jj = 0; jj < 13; jj++) s += es[i][qq + 4 * jj];
    s += __shfl_xor(s, 1);
    s += __shfl_xor(s, 2);
    if (qq == 0) inv[i] = 1.0f / s;
  }
  __syncthreads();

  // ---- P*V: 2i x 4d tiles, 200 threads ----
  int wy = nw / NWW, wx = nw % NWW;
  if (tid < 200) {
    int ig = tid >> 3, dg = tid & 7;
    int i0 = ig * 2, d4 = dg * 4;
    float a[2][4] = {};
    for (int j = 0; j < 52; j += 4) {
      float4 e0 = *(const float4*)&es[i0][j];
      float4 e1 = *(const float4*)&es[i0 + 1][j];
#pragma unroll
      for (int jj = 0; jj < 4; jj++) {
        float4 vv = *(const float4*)&vs[j + jj][d4];
        float ee0 = ((const float*)&e0)[jj];
        float ee1 = ((const float*)&e1)[jj];
        a[0][0] = fmaf(ee0, vv.x, a[0][0]); a[0][1] = fmaf(ee0, vv.y, a[0][1]);
        a[0][2] = fmaf(ee0, vv.z, a[0][2]); a[0][3] = fmaf(ee0, vv.w, a[0][3]);
        a[1][0] = fmaf(ee1, vv.x, a[1][0]); a[1][1] = fmaf(ee1, vv.y, a[1][1]);
        a[1][2] = fmaf(ee1, vv.z, a[1][2]); a[1][3] = fmaf(ee1, vv.w, a[1][3]);
      }
    }
#pragma unroll
    for (int ii = 0; ii < 2; ii++) {
      int i = i0 + ii;
      if (i >= WS2) continue;
      float iv = inv[i];
      int py = i / WS_, px = i % WS_;
      int hsp = wy * WS_ + py, wsp = wx * WS_ + px;
      size_t o = ((size_t)(b * HH + hsp) * WW + wsp) * HIDDEN + head * HD + d4;
      bf16x4 st;
      st.a = __float2bfloat16(a[ii][0] * iv);
      st.b = __float2bfloat16(a[ii][1] * iv);
      st.c = __float2bfloat16(a[ii][2] * iv);
      st.d = __float2bfloat16(a[ii][3] * iv);
      *(bf16x4*)&attn_out[o] = st;    // 8B packed store
    }
  }
}

// ---------------- Kernel 3: un-shift gather + output projection -----------
template <typename T>
__global__ __launch_bounds__(256, 2) void proj_kernel(
    const T* __restrict__ attn, const float* __restrict__ w_out,
    const float* __restrict__ b_out, float* __restrict__ out) {
  __shared__ float xs[64][100];
  __shared__ float wc[96][100];   // full weight resident
  int tid = threadIdx.x;
  int t0 = blockIdx.x * 64;

  for (int idx = tid; idx < 64 * 96; idx += 256) {
    int tl = idx / 96, ch = idx % 96;
    int tok = t0 + tl;
    int b = tok / (HH * WW); int rem = tok % (HH * WW);
    int h = rem / WW, w = rem % WW;
    int hs = (h - DISP + HH) % HH, wsp = (w - DISP + WW) % WW;  // roll(out,+3,+3)
    xs[tl][ch] = decT<T>(attn[((size_t)(b * HH + hs) * WW + wsp) * HIDDEN + ch]);
  }
  for (int idx = tid; idx < 96 * 96; idx += 256) {
    int r = idx / 96, c = idx - r * 96;
    wc[r][c] = w_out[idx];
  }
  __syncthreads();

  int colg = tid & 31, tg = tid >> 5;
  float acc[8][3];
#pragma unroll
  for (int j = 0; j < 3; j++) {
    float bj = b_out[colg + 32 * j];
#pragma unroll
    for (int t = 0; t < 8; t++) acc[t][j] = bj;
  }

  for (int kk = 0; kk < 96; kk += 4) {
    float4 xv[8];
#pragma unroll
    for (int t = 0; t < 8; t++) xv[t] = *(const float4*)&xs[tg * 8 + t][kk];
#pragma unroll
    for (int j = 0; j < 3; j++) {
      int c = colg + 32 * j;
      float w0 = wc[kk + 0][c], w1 = wc[kk + 1][c];
      float w2 = wc[kk + 2][c], w3 = wc[kk + 3][c];
#pragma unroll
      for (int t = 0; t < 8; t++) {
        acc[t][j] = fmaf(xv[t].x, w0, acc[t][j]);
        acc[t][j] = fmaf(xv[t].y, w1, acc[t][j]);
        acc[t][j] = fmaf(xv[t].z, w2, acc[t][j]);
        acc[t][j] = fmaf(xv[t].w, w3, acc[t][j]);
      }
    }
  }

#pragma unroll
  for (int j = 0; j < 3; j++)
#pragma unroll
    for (int t = 0; t < 8; t++)
      out[(size_t)(t0 + tg * 8 + t) * HIDDEN + colg + 32 * j] = acc[t][j];
}

extern "C" void kernel_launch(void* const* d_in, const int* in_sizes, int n_in,
                              void* d_out, int out_size, void* d_ws, size_t ws_size,
                              hipStream_t stream) {
  const float* x     = (const float*)d_in[0];
  const float* w_qkv = (const float*)d_in[1];
  const float* b_qkv = (const float*)d_in[2];
  const float* pos   = (const float*)d_in[3];
  const float* w_out = (const float*)d_in[4];
  const float* b_out = (const float*)d_in[5];
  float* out = (float*)d_out;

  bf16* qb = (bf16*)d_ws;
  bf16* kb = qb + QKV_ELEMS;
  bf16* vb = kb + QKV_ELEMS;
  bf16* ab = vb + QKV_ELEMS;
  qkv_win_kernel<bf16><<<TOKENS / 64, 256, 0, stream>>>(x, w_qkv, b_qkv, qb, kb, vb);
  attn_kernel<<<B_ * HEADS * NW, 256, 0, stream>>>(qb, kb, vb, pos, ab);
  proj_kernel<bf16><<<TOKENS / 64, 256, 0, stream>>>(ab, w_out, b_out, out);
}

// Round 8
// 256.551 us; speedup vs baseline: 4.1862x; 1.6065x over previous
//
#include <hip/hip_runtime.h>
#include <hip/hip_bf16.h>

using bf16 = __hip_bfloat16;
typedef __attribute__((ext_vector_type(8))) short short8;
typedef __attribute__((ext_vector_type(4))) float floatx4;

#define B_      32
#define HH      56
#define WW      56
#define HIDDEN  96
#define HEADS   3
#define HD      32
#define WS_     7
#define DISP    3
#define NWH     8
#define NWW     8
#define NW      64
#define WS2     49
#define TOKENS  (B_*HH*WW)                        /* 100352 */
#define QKV_ELEMS ((size_t)B_*HEADS*NW*WS2*HD)    /* 9,633,792 */

struct alignas(8) bf16x4 { bf16 a, b, c, d; };

__device__ inline unsigned short bf16_bits(float f) {   // RNE, matches __float2bfloat16
  unsigned u = __float_as_uint(f);
  unsigned r = u + 0x7fffu + ((u >> 16) & 1u);
  return (unsigned short)(r >> 16);
}

// ---------------- Kernel 1: shifted gather + QKV projection (MFMA) --------
// 64 tokens/block, 4 waves. Chunks ci=0/1/2 are q/k/v (96 cols each).
// Wave wv owns tokens [16wv,16wv+16); 6 col-tiles x 3 k-blocks of
// mfma_f32_16x16x32_bf16. A: m=lane&15, k=(lane>>4)*8+j. B mirrored.
// C/D: col=lane&15, row=(lane>>4)*4+reg.
__global__ __launch_bounds__(256) void qkv_mfma_kernel(
    const float* __restrict__ x, const float* __restrict__ w_qkv,
    const float* __restrict__ b_qkv,
    bf16* __restrict__ q, bf16* __restrict__ k, bf16* __restrict__ v) {
  __shared__ bf16 xs[64][112];   // 14.3 KB; 224B rows (16B aligned)
  __shared__ bf16 wT[96][104];   // 20.0 KB; [col][k] transposed, 208B rows
  int tid = threadIdx.x;
  int t0 = blockIdx.x * 64;
  int lane = tid & 63, wv = tid >> 6;
  int rowq = lane >> 4, n_ = lane & 15;

  // ---- stage x tile (roll -3,-3 gather), f32 -> bf16 ----
  for (int idx = tid; idx < 64 * 24; idx += 256) {
    int tl = idx / 24, seg = idx % 24;
    int tok = t0 + tl;
    int b = tok / (HH * WW); int rem = tok % (HH * WW);
    int hs = rem / WW, wsp = rem % WW;
    int h = (hs + DISP) % HH, w = (wsp + DISP) % WW;
    float4 xv = *(const float4*)&x[((size_t)(b * HH + h) * WW + w) * HIDDEN + seg * 4];
    bf16x4 pk;
    pk.a = __float2bfloat16(xv.x); pk.b = __float2bfloat16(xv.y);
    pk.c = __float2bfloat16(xv.z); pk.d = __float2bfloat16(xv.w);
    *(bf16x4*)&xs[tl][seg * 4] = pk;
  }

  // ---- per-lane output bases for the 4 C/D rows ----
  size_t tb[4];
#pragma unroll
  for (int r = 0; r < 4; r++) {
    int tok = t0 + 16 * wv + 4 * rowq + r;
    int b = tok / (HH * WW); int rem = tok % (HH * WW);
    int hs = rem / WW, wsp = rem % WW;
    int wy = hs / WS_, py = hs % WS_, wx = wsp / WS_, px = wsp % WS_;
    tb[r] = (size_t)b * (HEADS * NW * WS2 * HD) +
            (size_t)((wy * NWW + wx) * WS2 + (py * WS_ + px)) * HD;
  }

  __syncthreads();

  // ---- A fragments (reused across all 3 chunks) ----
  short8 afrag[3];
  {
    int m = 16 * wv + n_;
    int kq = rowq * 8;
#pragma unroll
    for (int kb = 0; kb < 3; kb++)
      afrag[kb] = *(const short8*)&xs[m][kb * 32 + kq];
  }

  for (int ci = 0; ci < 3; ci++) {
    __syncthreads();   // previous chunk's wT reads done
    // stage wT[c][k] bf16, packed k-pairs (2-way banks: free)
    for (int idx = tid; idx < 48 * 96; idx += 256) {
      int kp = idx / 96, c = idx % 96;
      unsigned lo = bf16_bits(w_qkv[(2 * kp) * 288 + ci * 96 + c]);
      unsigned hi = bf16_bits(w_qkv[(2 * kp + 1) * 288 + ci * 96 + c]);
      *(unsigned*)&wT[c][2 * kp] = lo | (hi << 16);
    }
    __syncthreads();

    int kq = rowq * 8;
    floatx4 acc[6];
#pragma unroll
    for (int c6 = 0; c6 < 6; c6++) {
      float bias = b_qkv[ci * 96 + c6 * 16 + n_];
      acc[c6] = (floatx4){bias, bias, bias, bias};
    }
#pragma unroll
    for (int c6 = 0; c6 < 6; c6++) {
#pragma unroll
      for (int kb = 0; kb < 3; kb++) {
        short8 bfrag = *(const short8*)&wT[c6 * 16 + n_][kb * 32 + kq];
        acc[c6] = __builtin_amdgcn_mfma_f32_16x16x32_bf16(afrag[kb], bfrag, acc[c6], 0, 0, 0);
      }
    }

    bf16* dst = (ci == 0) ? q : (ci == 1) ? k : v;
#pragma unroll
    for (int c6 = 0; c6 < 6; c6++) {
      int col = c6 * 16 + n_;            // 0..95 within chunk
      size_t hoff = (size_t)(col >> 5) * (NW * WS2 * HD) + (col & 31);
#pragma unroll
      for (int r = 0; r < 4; r++)
        dst[tb[r] + hoff] = __float2bfloat16(acc[c6][r]);
    }
  }
}

// ---------------- Kernel 2: per-window attention (unchanged, R7) ----------
__device__ inline void unpack8(float* dst, uint4 u) {
  dst[0] = __uint_as_float(u.x << 16); dst[1] = __uint_as_float(u.x & 0xffff0000u);
  dst[2] = __uint_as_float(u.y << 16); dst[3] = __uint_as_float(u.y & 0xffff0000u);
  dst[4] = __uint_as_float(u.z << 16); dst[5] = __uint_as_float(u.z & 0xffff0000u);
  dst[6] = __uint_as_float(u.w << 16); dst[7] = __uint_as_float(u.w & 0xffff0000u);
}

__global__ __launch_bounds__(256) void attn_kernel(
    const bf16* __restrict__ q, const bf16* __restrict__ k,
    const bf16* __restrict__ v, const float* __restrict__ pos_emb,
    bf16* __restrict__ attn_out) {
  int blk = blockIdx.x;                 // b*192 + head*64 + nw
  int nw = blk % NW; int t2 = blk / NW;
  int head = t2 % HEADS; int b = t2 / HEADS;

  __shared__ float qs[52][36], ks[52][36], vs[52][36];
  __shared__ float es[49][60];
  __shared__ float pel[169];
  __shared__ float inv[49];
  int tid = threadIdx.x;

  size_t base = ((size_t)(b * HEADS + head) * NW + nw) * (WS2 * HD);
  if (tid < 196) {
    int row = tid >> 2, d0 = (tid & 3) * 8;
    uint4 uq = ((const uint4*)(q + base))[tid];
    uint4 uk = ((const uint4*)(k + base))[tid];
    uint4 uv = ((const uint4*)(v + base))[tid];
    unpack8(&qs[row][d0], uq);
    unpack8(&ks[row][d0], uk);
    unpack8(&vs[row][d0], uv);
  }
  for (int i = tid; i < 3 * 36; i += 256) {
    int r = 49 + i / 36, c = i % 36;
    qs[r][c] = 0.f; ks[r][c] = 0.f; vs[r][c] = 0.f;
  }
  for (int i = tid; i < 49 * 3; i += 256) es[i / 3][49 + i % 3] = 0.f;
  for (int i = tid; i < 169; i += 256) pel[i] = pos_emb[i];
  __syncthreads();

  const float scale = 0.10206207261596575f;   // 96^-0.5
  bool masked = (nw >= NW - NWW);

  if (tid < 221) {
    int ig = tid / 17, jg = tid % 17;
    int i0 = ig * 4, j0 = jg * 3;
    float acc[4][3] = {};
    for (int kk = 0; kk < 32; kk += 4) {
      float4 kv0 = *(const float4*)&ks[j0 + 0][kk];
      float4 kv1 = *(const float4*)&ks[j0 + 1][kk];
      float4 kv2 = *(const float4*)&ks[j0 + 2][kk];
#pragma unroll
      for (int ii = 0; ii < 4; ii++) {
        float4 qv = *(const float4*)&qs[i0 + ii][kk];
        acc[ii][0] += qv.x * kv0.x + qv.y * kv0.y + qv.z * kv0.z + qv.w * kv0.w;
        acc[ii][1] += qv.x * kv1.x + qv.y * kv1.y + qv.z * kv1.z + qv.w * kv1.w;
        acc[ii][2] += qv.x * kv2.x + qv.y * kv2.y + qv.z * kv2.z + qv.w * kv2.w;
      }
    }
#pragma unroll
    for (int ii = 0; ii < 4; ii++) {
      int i = i0 + ii;
      if (i >= WS2) break;
      int yi = i / WS_, xi = i % WS_;
#pragma unroll
      for (int jj = 0; jj < 3; jj++) {
        int j = j0 + jj;
        if (j >= WS2) continue;
        bool dead = masked && ((i >= 28) != (j >= 28));
        float e = 0.f;
        if (!dead) {
          int yj = j / WS_, xj = j % WS_;
          e = __expf(acc[ii][jj] * scale + pel[(yj - yi + 6) * 13 + (xj - xi + 6)]);
        }
        es[i][j] = e;
      }
    }
  }
  __syncthreads();

  if (tid < 196) {
    int i = tid >> 2, qq = tid & 3;
    float s = 0.f;
#pragma unroll
    for (int jj = 0; jj < 13; jj++) s += es[i][qq + 4 * jj];
    s += __shfl_xor(s, 1);
    s += __shfl_xor(s, 2);
    if (qq == 0) inv[i] = 1.0f / s;
  }
  __syncthreads();

  int wy = nw / NWW, wx = nw % NWW;
  if (tid < 200) {
    int ig = tid >> 3, dg = tid & 7;
    int i0 = ig * 2, d4 = dg * 4;
    float a[2][4] = {};
    for (int j = 0; j < 52; j += 4) {
      float4 e0 = *(const float4*)&es[i0][j];
      float4 e1 = *(const float4*)&es[i0 + 1][j];
#pragma unroll
      for (int jj = 0; jj < 4; jj++) {
        float4 vv = *(const float4*)&vs[j + jj][d4];
        float ee0 = ((const float*)&e0)[jj];
        float ee1 = ((const float*)&e1)[jj];
        a[0][0] = fmaf(ee0, vv.x, a[0][0]); a[0][1] = fmaf(ee0, vv.y, a[0][1]);
        a[0][2] = fmaf(ee0, vv.z, a[0][2]); a[0][3] = fmaf(ee0, vv.w, a[0][3]);
        a[1][0] = fmaf(ee1, vv.x, a[1][0]); a[1][1] = fmaf(ee1, vv.y, a[1][1]);
        a[1][2] = fmaf(ee1, vv.z, a[1][2]); a[1][3] = fmaf(ee1, vv.w, a[1][3]);
      }
    }
#pragma unroll
    for (int ii = 0; ii < 2; ii++) {
      int i = i0 + ii;
      if (i >= WS2) continue;
      float iv = inv[i];
      int py = i / WS_, px = i % WS_;
      int hsp = wy * WS_ + py, wsp = wx * WS_ + px;
      size_t o = ((size_t)(b * HH + hsp) * WW + wsp) * HIDDEN + head * HD + d4;
      bf16x4 st;
      st.a = __float2bfloat16(a[ii][0] * iv);
      st.b = __float2bfloat16(a[ii][1] * iv);
      st.c = __float2bfloat16(a[ii][2] * iv);
      st.d = __float2bfloat16(a[ii][3] * iv);
      *(bf16x4*)&attn_out[o] = st;
    }
  }
}

// ---------------- Kernel 3: un-shift gather + output projection (MFMA) ----
__global__ __launch_bounds__(256) void proj_mfma_kernel(
    const bf16* __restrict__ attn, const float* __restrict__ w_out,
    const float* __restrict__ b_out, float* __restrict__ out) {
  __shared__ bf16 xs[64][112];
  __shared__ bf16 wT[96][104];
  int tid = threadIdx.x;
  int t0 = blockIdx.x * 64;
  int lane = tid & 63, wv = tid >> 6;
  int rowq = lane >> 4, n_ = lane & 15;

  // attn rows are contiguous bf16: copy 16B chunks with roll(+3,+3) gather
  for (int idx = tid; idx < 64 * 12; idx += 256) {
    int tl = idx / 12, seg = idx % 12;
    int tok = t0 + tl;
    int b = tok / (HH * WW); int rem = tok % (HH * WW);
    int h = rem / WW, w = rem % WW;
    int hs = (h - DISP + HH) % HH, wsp = (w - DISP + WW) % WW;
    uint4 u = *(const uint4*)&attn[((size_t)(b * HH + hs) * WW + wsp) * HIDDEN + seg * 8];
    *(uint4*)&xs[tl][seg * 8] = u;
  }
  for (int idx = tid; idx < 48 * 96; idx += 256) {
    int kp = idx / 96, c = idx % 96;
    unsigned lo = bf16_bits(w_out[(2 * kp) * 96 + c]);
    unsigned hi = bf16_bits(w_out[(2 * kp + 1) * 96 + c]);
    *(unsigned*)&wT[c][2 * kp] = lo | (hi << 16);
  }
  __syncthreads();

  int kq = rowq * 8;
  short8 afrag[3];
  {
    int m = 16 * wv + n_;
#pragma unroll
    for (int kb = 0; kb < 3; kb++)
      afrag[kb] = *(const short8*)&xs[m][kb * 32 + kq];
  }

  floatx4 acc[6];
#pragma unroll
  for (int c6 = 0; c6 < 6; c6++) {
    float bias = b_out[c6 * 16 + n_];
    acc[c6] = (floatx4){bias, bias, bias, bias};
  }
#pragma unroll
  for (int c6 = 0; c6 < 6; c6++) {
#pragma unroll
    for (int kb = 0; kb < 3; kb++) {
      short8 bfrag = *(const short8*)&wT[c6 * 16 + n_][kb * 32 + kq];
      acc[c6] = __builtin_amdgcn_mfma_f32_16x16x32_bf16(afrag[kb], bfrag, acc[c6], 0, 0, 0);
    }
  }

#pragma unroll
  for (int c6 = 0; c6 < 6; c6++) {
#pragma unroll
    for (int r = 0; r < 4; r++)
      out[(size_t)(t0 + 16 * wv + 4 * rowq + r) * HIDDEN + c6 * 16 + n_] = acc[c6][r];
  }
}

extern "C" void kernel_launch(void* const* d_in, const int* in_sizes, int n_in,
                              void* d_out, int out_size, void* d_ws, size_t ws_size,
                              hipStream_t stream) {
  const float* x     = (const float*)d_in[0];
  const float* w_qkv = (const float*)d_in[1];
  const float* b_qkv = (const float*)d_in[2];
  const float* pos   = (const float*)d_in[3];
  const float* w_out = (const float*)d_in[4];
  const float* b_out = (const float*)d_in[5];
  float* out = (float*)d_out;

  bf16* qb = (bf16*)d_ws;
  bf16* kb = qb + QKV_ELEMS;
  bf16* vb = kb + QKV_ELEMS;
  bf16* ab = vb + QKV_ELEMS;
  qkv_mfma_kernel<<<TOKENS / 64, 256, 0, stream>>>(x, w_qkv, b_qkv, qb, kb, vb);
  attn_kernel<<<B_ * HEADS * NW, 256, 0, stream>>>(qb, kb, vb, pos, ab);
  proj_mfma_kernel<<<TOKENS / 64, 256, 0, stream>>>(ab, w_out, b_out, out);
}

// Round 9
// 160.376 us; speedup vs baseline: 6.6966x; 1.5997x over previous
//
#include <hip/hip_runtime.h>
#include <hip/hip_bf16.h>

using bf16 = __hip_bfloat16;
typedef __attribute__((ext_vector_type(8))) short short8;
typedef __attribute__((ext_vector_type(4))) float floatx4;

#define B_      32
#define HH      56
#define WW      56
#define HIDDEN  96
#define HEADS   3
#define HD      32
#define WS_     7
#define DISP    3
#define NWH     8
#define NWW     8
#define NW      64
#define WS2     49
#define TOKENS  (B_*HH*WW)                        /* 100352 */
#define QKV_ELEMS ((size_t)B_*HEADS*NW*WS2*HD)    /* 9,633,792 */

struct alignas(8) bf16x4 { bf16 a, b, c, d; };

__device__ inline unsigned short bf16_bits(float f) {   // RNE, matches __float2bfloat16
  unsigned u = __float_as_uint(f);
  unsigned r = u + 0x7fffu + ((u >> 16) & 1u);
  return (unsigned short)(r >> 16);
}

// ---------------- Kernel 1: shifted gather + QKV projection (MFMA) --------
__global__ __launch_bounds__(256) void qkv_mfma_kernel(
    const float* __restrict__ x, const float* __restrict__ w_qkv,
    const float* __restrict__ b_qkv,
    bf16* __restrict__ q, bf16* __restrict__ k, bf16* __restrict__ v) {
  __shared__ bf16 xs[64][112];   // 14.3 KB
  __shared__ bf16 wT[96][104];   // 20.0 KB; [col][k]
  int tid = threadIdx.x;
  int t0 = blockIdx.x * 64;
  int lane = tid & 63, wv = tid >> 6;
  int rowq = lane >> 4, n_ = lane & 15;

  for (int idx = tid; idx < 64 * 24; idx += 256) {
    int tl = idx / 24, seg = idx % 24;
    int tok = t0 + tl;
    int b = tok / (HH * WW); int rem = tok % (HH * WW);
    int hs = rem / WW, wsp = rem % WW;
    int h = (hs + DISP) % HH, w = (wsp + DISP) % WW;
    float4 xv = *(const float4*)&x[((size_t)(b * HH + h) * WW + w) * HIDDEN + seg * 4];
    bf16x4 pk;
    pk.a = __float2bfloat16(xv.x); pk.b = __float2bfloat16(xv.y);
    pk.c = __float2bfloat16(xv.z); pk.d = __float2bfloat16(xv.w);
    *(bf16x4*)&xs[tl][seg * 4] = pk;
  }

  size_t tb[4];
#pragma unroll
  for (int r = 0; r < 4; r++) {
    int tok = t0 + 16 * wv + 4 * rowq + r;
    int b = tok / (HH * WW); int rem = tok % (HH * WW);
    int hs = rem / WW, wsp = rem % WW;
    int wy = hs / WS_, py = hs % WS_, wx = wsp / WS_, px = wsp % WS_;
    tb[r] = (size_t)b * (HEADS * NW * WS2 * HD) +
            (size_t)((wy * NWW + wx) * WS2 + (py * WS_ + px)) * HD;
  }

  __syncthreads();

  short8 afrag[3];
  {
    int m = 16 * wv + n_;
    int kq = rowq * 8;
#pragma unroll
    for (int kb = 0; kb < 3; kb++)
      afrag[kb] = *(const short8*)&xs[m][kb * 32 + kq];
  }

  for (int ci = 0; ci < 3; ci++) {
    __syncthreads();
    for (int idx = tid; idx < 48 * 96; idx += 256) {
      int kp = idx / 96, c = idx % 96;
      unsigned lo = bf16_bits(w_qkv[(2 * kp) * 288 + ci * 96 + c]);
      unsigned hi = bf16_bits(w_qkv[(2 * kp + 1) * 288 + ci * 96 + c]);
      *(unsigned*)&wT[c][2 * kp] = lo | (hi << 16);
    }
    __syncthreads();

    int kq = rowq * 8;
    floatx4 acc[6];
#pragma unroll
    for (int c6 = 0; c6 < 6; c6++) {
      float bias = b_qkv[ci * 96 + c6 * 16 + n_];
      acc[c6] = (floatx4){bias, bias, bias, bias};
    }
#pragma unroll
    for (int c6 = 0; c6 < 6; c6++) {
#pragma unroll
      for (int kb = 0; kb < 3; kb++) {
        short8 bfrag = *(const short8*)&wT[c6 * 16 + n_][kb * 32 + kq];
        acc[c6] = __builtin_amdgcn_mfma_f32_16x16x32_bf16(afrag[kb], bfrag, acc[c6], 0, 0, 0);
      }
    }

    bf16* dst = (ci == 0) ? q : (ci == 1) ? k : v;
#pragma unroll
    for (int c6 = 0; c6 < 6; c6++) {
      int col = c6 * 16 + n_;
      size_t hoff = (size_t)(col >> 5) * (NW * WS2 * HD) + (col & 31);
#pragma unroll
      for (int r = 0; r < 4; r++)
        dst[tb[r] + hoff] = __float2bfloat16(acc[c6][r]);
    }
  }
}

// ---------------- Kernel 2: per-window attention (MFMA) -------------------
// One block per (b,head,nw); 4 waves; wave w owns S/O rows [16w,16w+16).
// S = Q.K^T via mfma_16x16x32 (B-frag of Q.K^T == K rows: no transpose!).
// exp+bias+mask in C-layout regs; rowsum via shfl; 1/sum folded into P;
// P round-trips LDS as bf16 A-frags; V staged transposed for B-frags.
__global__ __launch_bounds__(256) void attn_kernel(
    const bf16* __restrict__ q, const bf16* __restrict__ k,
    const bf16* __restrict__ v, const float* __restrict__ pos_emb,
    bf16* __restrict__ attn_out) {
  int blk = blockIdx.x;                 // b*192 + head*64 + nw
  int nw = blk % NW; int t2 = blk / NW;
  int head = t2 % HEADS; int b = t2 / HEADS;

  __shared__ unsigned short qs[64 * 40];   // [row][d], stride 40 (80B: 2-way banks)
  __shared__ unsigned short ks[64 * 40];
  __shared__ unsigned short vTs[32 * 72];  // [d][j], stride 72
  __shared__ unsigned short es[64 * 72];   // P (normalized), bf16, stride 72
  __shared__ float pel[169];
  int tid = threadIdx.x;
  int lane = tid & 63, wv = tid >> 6;
  int n_ = lane & 15, quad = lane >> 4;

  size_t base = ((size_t)(b * HEADS + head) * NW + nw) * (WS2 * HD);
  const uint4* qg = (const uint4*)(q + base);
  const uint4* kg = (const uint4*)(k + base);
  const uint4* vg = (const uint4*)(v + base);

  // stage q/k: direct 16B copies (49 rows x 4 chunks)
  for (int c = tid; c < 196; c += 256) {
    int row = c >> 2, seg = c & 3;
    *(uint4*)&qs[row * 40 + seg * 8] = qg[c];
    *(uint4*)&ks[row * 40 + seg * 8] = kg[c];
  }
  // stage v transposed, lane-rotated scatter (conflict-free)
  for (int c = tid; c < 196; c += 256) {
    int j = c >> 2, d0 = (c & 3) * 8;
    uint4 u4 = vg[c];
    unsigned short vals[8];
    vals[0] = u4.x & 0xffff; vals[1] = u4.x >> 16;
    vals[2] = u4.y & 0xffff; vals[3] = u4.y >> 16;
    vals[4] = u4.z & 0xffff; vals[5] = u4.z >> 16;
    vals[6] = u4.w & 0xffff; vals[7] = u4.w >> 16;
    int rot = c & 7;
#pragma unroll
    for (int u = 0; u < 8; u++) {
      int ue = (u + rot) & 7;
      vTs[(d0 + ue) * 72 + j] = vals[ue];
    }
  }
  // zero pads: q/k rows 49-63; vT cols 49-63
  for (int idx = tid; idx < 75; idx += 256) {          // 15 rows x 40 = 600 ush = 75 uint4
    ((uint4*)&qs[49 * 40])[idx] = (uint4){0, 0, 0, 0};
    ((uint4*)&ks[49 * 40])[idx] = (uint4){0, 0, 0, 0};
  }
  for (int idx = tid; idx < 32 * 15; idx += 256) {
    int d = idx / 15, j = 49 + idx % 15;
    vTs[d * 72 + j] = 0;
  }
  for (int i = tid; i < 169; i += 256) pel[i] = pos_emb[i];
  __syncthreads();

  const float scale = 0.10206207261596575f;   // 96^-0.5 (HIDDEN, per reference)
  bool masked = (nw >= NW - NWW);

  // ---- QK^T: 1 A-frag, 4 B-frags, 4 mfma ----
  short8 aq = *(const short8*)&qs[(16 * wv + n_) * 40 + quad * 8];
  floatx4 sAcc[4];
  const floatx4 zero4 = (floatx4){0.f, 0.f, 0.f, 0.f};
#pragma unroll
  for (int jt = 0; jt < 4; jt++) {
    short8 bk = *(const short8*)&ks[(16 * jt + n_) * 40 + quad * 8];
    sAcc[jt] = __builtin_amdgcn_mfma_f32_16x16x32_bf16(aq, bk, zero4, 0, 0, 0);
  }

  // ---- exp + bias + mask in regs; row sums; fold 1/sum; write P to LDS ----
  float ei[4][4];        // [jt][r]
  float rowsum[4] = {0.f, 0.f, 0.f, 0.f};
#pragma unroll
  for (int r = 0; r < 4; r++) {
    int i_r = 16 * wv + 4 * quad + r;
    int yi = i_r / WS_, xi = i_r % WS_;
#pragma unroll
    for (int jt = 0; jt < 4; jt++) {
      int j = 16 * jt + n_;
      int idx = (j / WS_ - yi + 6) * 13 + (j % WS_ - xi + 6);
      idx = idx < 0 ? 0 : (idx > 168 ? 168 : idx);
      float e = __expf(sAcc[jt][r] * scale + pel[idx]);
      bool live = (j < WS2) && (i_r < WS2) &&
                  !(masked && ((i_r >= 28) != (j >= 28)));
      e = live ? e : 0.f;
      ei[jt][r] = e;
      rowsum[r] += e;
    }
  }
#pragma unroll
  for (int r = 0; r < 4; r++) {
    float s = rowsum[r];
    s += __shfl_xor(s, 1); s += __shfl_xor(s, 2);
    s += __shfl_xor(s, 4); s += __shfl_xor(s, 8);
    float inv = s > 0.f ? 1.0f / s : 0.f;
    int i_r = 16 * wv + 4 * quad + r;
#pragma unroll
    for (int jt = 0; jt < 4; jt++)
      es[i_r * 72 + 16 * jt + n_] = bf16_bits(ei[jt][r] * inv);
  }
  __syncthreads();

  // ---- P*V: A-frags from es, B-frags from vT ----
  short8 ap[2];
#pragma unroll
  for (int kc = 0; kc < 2; kc++)
    ap[kc] = *(const short8*)&es[(16 * wv + n_) * 72 + 32 * kc + quad * 8];
  floatx4 oAcc[2] = {zero4, zero4};
#pragma unroll
  for (int nt = 0; nt < 2; nt++) {
#pragma unroll
    for (int kc = 0; kc < 2; kc++) {
      short8 bv = *(const short8*)&vTs[(16 * nt + n_) * 72 + 32 * kc + quad * 8];
      oAcc[nt] = __builtin_amdgcn_mfma_f32_16x16x32_bf16(ap[kc], bv, oAcc[nt], 0, 0, 0);
    }
  }

  // ---- store O ----
  int wy = nw / NWW, wx = nw % NWW;
#pragma unroll
  for (int r = 0; r < 4; r++) {
    int i_r = 16 * wv + 4 * quad + r;
    if (i_r < WS2) {
      int py = i_r / WS_, px = i_r % WS_;
      int hsp = wy * WS_ + py, wsp = wx * WS_ + px;
      size_t o = ((size_t)(b * HH + hsp) * WW + wsp) * HIDDEN + head * HD;
#pragma unroll
      for (int nt = 0; nt < 2; nt++)
        attn_out[o + 16 * nt + n_] = __float2bfloat16(oAcc[nt][r]);
    }
  }
}

// ---------------- Kernel 3: un-shift gather + output projection (MFMA) ----
__global__ __launch_bounds__(256) void proj_mfma_kernel(
    const bf16* __restrict__ attn, const float* __restrict__ w_out,
    const float* __restrict__ b_out, float* __restrict__ out) {
  __shared__ bf16 xs[64][112];
  __shared__ bf16 wT[96][104];
  int tid = threadIdx.x;
  int t0 = blockIdx.x * 64;
  int lane = tid & 63, wv = tid >> 6;
  int rowq = lane >> 4, n_ = lane & 15;

  for (int idx = tid; idx < 64 * 12; idx += 256) {
    int tl = idx / 12, seg = idx % 12;
    int tok = t0 + tl;
    int b = tok / (HH * WW); int rem = tok % (HH * WW);
    int h = rem / WW, w = rem % WW;
    int hs = (h - DISP + HH) % HH, wsp = (w - DISP + WW) % WW;
    uint4 u = *(const uint4*)&attn[((size_t)(b * HH + hs) * WW + wsp) * HIDDEN + seg * 8];
    *(uint4*)&xs[tl][seg * 8] = u;
  }
  for (int idx = tid; idx < 48 * 96; idx += 256) {
    int kp = idx / 96, c = idx % 96;
    unsigned lo = bf16_bits(w_out[(2 * kp) * 96 + c]);
    unsigned hi = bf16_bits(w_out[(2 * kp + 1) * 96 + c]);
    *(unsigned*)&wT[c][2 * kp] = lo | (hi << 16);
  }
  __syncthreads();

  int kq = rowq * 8;
  short8 afrag[3];
  {
    int m = 16 * wv + n_;
#pragma unroll
    for (int kb = 0; kb < 3; kb++)
      afrag[kb] = *(const short8*)&xs[m][kb * 32 + kq];
  }

  floatx4 acc[6];
#pragma unroll
  for (int c6 = 0; c6 < 6; c6++) {
    float bias = b_out[c6 * 16 + n_];
    acc[c6] = (floatx4){bias, bias, bias, bias};
  }
#pragma unroll
  for (int c6 = 0; c6 < 6; c6++) {
#pragma unroll
    for (int kb = 0; kb < 3; kb++) {
      short8 bfrag = *(const short8*)&wT[c6 * 16 + n_][kb * 32 + kq];
      acc[c6] = __builtin_amdgcn_mfma_f32_16x16x32_bf16(afrag[kb], bfrag, acc[c6], 0, 0, 0);
    }
  }

#pragma unroll
  for (int c6 = 0; c6 < 6; c6++) {
#pragma unroll
    for (int r = 0; r < 4; r++)
      out[(size_t)(t0 + 16 * wv + 4 * rowq + r) * HIDDEN + c6 * 16 + n_] = acc[c6][r];
  }
}

extern "C" void kernel_launch(void* const* d_in, const int* in_sizes, int n_in,
                              void* d_out, int out_size, void* d_ws, size_t ws_size,
                              hipStream_t stream) {
  const float* x     = (const float*)d_in[0];
  const float* w_qkv = (const float*)d_in[1];
  const float* b_qkv = (const float*)d_in[2];
  const float* pos   = (const float*)d_in[3];
  const float* w_out = (const float*)d_in[4];
  const float* b_out = (const float*)d_in[5];
  float* out = (float*)d_out;

  bf16* qb = (bf16*)d_ws;
  bf16* kb = qb + QKV_ELEMS;
  bf16* vb = kb + QKV_ELEMS;
  bf16* ab = vb + QKV_ELEMS;
  qkv_mfma_kernel<<<TOKENS / 64, 256, 0, stream>>>(x, w_qkv, b_qkv, qb, kb, vb);
  attn_kernel<<<B_ * HEADS * NW, 256, 0, stream>>>(qb, kb, vb, pos, ab);
  proj_mfma_kernel<<<TOKENS / 64, 256, 0, stream>>>(ab, w_out, b_out, out);
}

// Round 10
// 157.305 us; speedup vs baseline: 6.8274x; 1.0195x over previous
//
#include <hip/hip_runtime.h>
#include <hip/hip_bf16.h>

using bf16 = __hip_bfloat16;
typedef __attribute__((ext_vector_type(8))) short short8;
typedef __attribute__((ext_vector_type(4))) float floatx4;

#define B_      32
#define HH      56
#define WW      56
#define HIDDEN  96
#define HEADS   3
#define HD      32
#define WS_     7
#define DISP    3
#define NWH     8
#define NWW     8
#define NW      64
#define WS2     49
#define TOKENS  (B_*HH*WW)                        /* 100352 */
#define QKV_ELEMS ((size_t)B_*HEADS*NW*WS2*HD)    /* 9,633,792 */
#define NFRAG_QKV (3*6*3*64)                      /* 3456 lane-frags */
#define NFRAG_OUT (6*3*64)                        /* 1152 lane-frags */

struct alignas(8) bf16x4 { bf16 a, b, c, d; };

// ---------------- Kernel 0: weight pre-swizzle into MFMA B-frag order -----
// wf[t*64+lane] (short8) = B-fragment for frag-tile t, lane l.
// qkv: t = (ci*6+c6)*3+kb, frag[j] = w_qkv[(kb*32+rowq*8+j)*288 + ci*96+c6*16+n_]
// out: t = c6*3+kb,        frag[j] = w_out [(kb*32+rowq*8+j)*96  + c6*16+n_]
__global__ __launch_bounds__(256) void prep_weights_kernel(
    const float* __restrict__ w_qkv, const float* __restrict__ w_out,
    bf16* __restrict__ wfq, bf16* __restrict__ wfo) {
  int f = blockIdx.x * 256 + threadIdx.x;
  if (f < NFRAG_QKV) {
    int lane = f & 63, t = f >> 6;
    int kb = t % 3, t2 = t / 3, c6 = t2 % 6, ci = t2 / 6;
    int col = ci * 96 + c6 * 16 + (lane & 15);
    int k0 = kb * 32 + (lane >> 4) * 8;
    bf16 vals[8];
#pragma unroll
    for (int j = 0; j < 8; j++) vals[j] = __float2bfloat16(w_qkv[(k0 + j) * 288 + col]);
    *(short8*)&wfq[(size_t)f * 8] = *(const short8*)vals;
  } else if (f < NFRAG_QKV + NFRAG_OUT) {
    int fo = f - NFRAG_QKV;
    int lane = fo & 63, t = fo >> 6;
    int kb = t % 3, c6 = t / 3;
    int col = c6 * 16 + (lane & 15);
    int k0 = kb * 32 + (lane >> 4) * 8;
    bf16 vals[8];
#pragma unroll
    for (int j = 0; j < 8; j++) vals[j] = __float2bfloat16(w_out[(k0 + j) * 96 + col]);
    *(short8*)&wfo[(size_t)fo * 8] = *(const short8*)vals;
  }
}

// ---------------- Kernel 1: shifted gather + QKV projection (MFMA) --------
__global__ __launch_bounds__(256) void qkv_mfma_kernel(
    const float* __restrict__ x, const bf16* __restrict__ wfq,
    const float* __restrict__ b_qkv,
    bf16* __restrict__ q, bf16* __restrict__ k, bf16* __restrict__ v) {
  __shared__ bf16 xs[64][112];   // 14.3 KB
  int tid = threadIdx.x;
  int t0 = blockIdx.x * 64;
  int lane = tid & 63, wv = tid >> 6;
  int rowq = lane >> 4, n_ = lane & 15;

  for (int idx = tid; idx < 64 * 24; idx += 256) {
    int tl = idx / 24, seg = idx % 24;
    int tok = t0 + tl;
    int b = tok / (HH * WW); int rem = tok % (HH * WW);
    int hs = rem / WW, wsp = rem % WW;
    int h = (hs + DISP) % HH, w = (wsp + DISP) % WW;
    float4 xv = *(const float4*)&x[((size_t)(b * HH + h) * WW + w) * HIDDEN + seg * 4];
    bf16x4 pk;
    pk.a = __float2bfloat16(xv.x); pk.b = __float2bfloat16(xv.y);
    pk.c = __float2bfloat16(xv.z); pk.d = __float2bfloat16(xv.w);
    *(bf16x4*)&xs[tl][seg * 4] = pk;
  }

  size_t tb[4];
#pragma unroll
  for (int r = 0; r < 4; r++) {
    int tok = t0 + 16 * wv + 4 * rowq + r;
    int b = tok / (HH * WW); int rem = tok % (HH * WW);
    int hs = rem / WW, wsp = rem % WW;
    int wy = hs / WS_, py = hs % WS_, wx = wsp / WS_, px = wsp % WS_;
    tb[r] = (size_t)b * (HEADS * NW * WS2 * HD) +
            (size_t)((wy * NWW + wx) * WS2 + (py * WS_ + px)) * HD;
  }

  __syncthreads();

  short8 afrag[3];
  {
    int m = 16 * wv + n_;
    int kq = rowq * 8;
#pragma unroll
    for (int kb = 0; kb < 3; kb++)
      afrag[kb] = *(const short8*)&xs[m][kb * 32 + kq];
  }

  const short8* wf = (const short8*)wfq;   // frag t, lane: wf[t*64+lane]
  for (int ci = 0; ci < 3; ci++) {
    bf16* dst = (ci == 0) ? q : (ci == 1) ? k : v;
#pragma unroll
    for (int c6 = 0; c6 < 6; c6++) {
      float bias = b_qkv[ci * 96 + c6 * 16 + n_];
      floatx4 acc = (floatx4){bias, bias, bias, bias};
#pragma unroll
      for (int kb = 0; kb < 3; kb++) {
        short8 bfrag = wf[(size_t)(((ci * 6 + c6) * 3 + kb) * 64 + lane)];
        acc = __builtin_amdgcn_mfma_f32_16x16x32_bf16(afrag[kb], bfrag, acc, 0, 0, 0);
      }
      int col = c6 * 16 + n_;
      size_t hoff = (size_t)(col >> 5) * (NW * WS2 * HD) + (col & 31);
#pragma unroll
      for (int r = 0; r < 4; r++)
        dst[tb[r] + hoff] = __float2bfloat16(acc[r]);
    }
  }
}

// ---------------- Kernel 2: per-window attention (MFMA, unchanged R9) -----
__device__ inline unsigned short bf16_bits(float f) {
  unsigned u = __float_as_uint(f);
  unsigned r = u + 0x7fffu + ((u >> 16) & 1u);
  return (unsigned short)(r >> 16);
}

__global__ __launch_bounds__(256) void attn_kernel(
    const bf16* __restrict__ q, const bf16* __restrict__ k,
    const bf16* __restrict__ v, const float* __restrict__ pos_emb,
    bf16* __restrict__ attn_out) {
  int blk = blockIdx.x;                 // b*192 + head*64 + nw
  int nw = blk % NW; int t2 = blk / NW;
  int head = t2 % HEADS; int b = t2 / HEADS;

  __shared__ unsigned short qs[64 * 40];
  __shared__ unsigned short ks[64 * 40];
  __shared__ unsigned short vTs[32 * 72];
  __shared__ unsigned short es[64 * 72];
  __shared__ float pel[169];
  int tid = threadIdx.x;
  int lane = tid & 63, wv = tid >> 6;
  int n_ = lane & 15, quad = lane >> 4;

  size_t base = ((size_t)(b * HEADS + head) * NW + nw) * (WS2 * HD);
  const uint4* qg = (const uint4*)(q + base);
  const uint4* kg = (const uint4*)(k + base);
  const uint4* vg = (const uint4*)(v + base);

  for (int c = tid; c < 196; c += 256) {
    int row = c >> 2, seg = c & 3;
    *(uint4*)&qs[row * 40 + seg * 8] = qg[c];
    *(uint4*)&ks[row * 40 + seg * 8] = kg[c];
  }
  for (int c = tid; c < 196; c += 256) {
    int j = c >> 2, d0 = (c & 3) * 8;
    uint4 u4 = vg[c];
    unsigned short vals[8];
    vals[0] = u4.x & 0xffff; vals[1] = u4.x >> 16;
    vals[2] = u4.y & 0xffff; vals[3] = u4.y >> 16;
    vals[4] = u4.z & 0xffff; vals[5] = u4.z >> 16;
    vals[6] = u4.w & 0xffff; vals[7] = u4.w >> 16;
    int rot = c & 7;
#pragma unroll
    for (int u = 0; u < 8; u++) {
      int ue = (u + rot) & 7;
      vTs[(d0 + ue) * 72 + j] = vals[ue];
    }
  }
  for (int idx = tid; idx < 75; idx += 256) {
    ((uint4*)&qs[49 * 40])[idx] = (uint4){0, 0, 0, 0};
    ((uint4*)&ks[49 * 40])[idx] = (uint4){0, 0, 0, 0};
  }
  for (int idx = tid; idx < 32 * 15; idx += 256) {
    int d = idx / 15, j = 49 + idx % 15;
    vTs[d * 72 + j] = 0;
  }
  for (int i = tid; i < 169; i += 256) pel[i] = pos_emb[i];
  __syncthreads();

  const float scale = 0.10206207261596575f;   // 96^-0.5
  bool masked = (nw >= NW - NWW);

  short8 aq = *(const short8*)&qs[(16 * wv + n_) * 40 + quad * 8];
  floatx4 sAcc[4];
  const floatx4 zero4 = (floatx4){0.f, 0.f, 0.f, 0.f};
#pragma unroll
  for (int jt = 0; jt < 4; jt++) {
    short8 bk = *(const short8*)&ks[(16 * jt + n_) * 40 + quad * 8];
    sAcc[jt] = __builtin_amdgcn_mfma_f32_16x16x32_bf16(aq, bk, zero4, 0, 0, 0);
  }

  float ei[4][4];
  float rowsum[4] = {0.f, 0.f, 0.f, 0.f};
#pragma unroll
  for (int r = 0; r < 4; r++) {
    int i_r = 16 * wv + 4 * quad + r;
    int yi = i_r / WS_, xi = i_r % WS_;
#pragma unroll
    for (int jt = 0; jt < 4; jt++) {
      int j = 16 * jt + n_;
      int idx = (j / WS_ - yi + 6) * 13 + (j % WS_ - xi + 6);
      idx = idx < 0 ? 0 : (idx > 168 ? 168 : idx);
      float e = __expf(sAcc[jt][r] * scale + pel[idx]);
      bool live = (j < WS2) && (i_r < WS2) &&
                  !(masked && ((i_r >= 28) != (j >= 28)));
      e = live ? e : 0.f;
      ei[jt][r] = e;
      rowsum[r] += e;
    }
  }
#pragma unroll
  for (int r = 0; r < 4; r++) {
    float s = rowsum[r];
    s += __shfl_xor(s, 1); s += __shfl_xor(s, 2);
    s += __shfl_xor(s, 4); s += __shfl_xor(s, 8);
    float inv = s > 0.f ? 1.0f / s : 0.f;
    int i_r = 16 * wv + 4 * quad + r;
#pragma unroll
    for (int jt = 0; jt < 4; jt++)
      es[i_r * 72 + 16 * jt + n_] = bf16_bits(ei[jt][r] * inv);
  }
  __syncthreads();

  short8 ap[2];
#pragma unroll
  for (int kc = 0; kc < 2; kc++)
    ap[kc] = *(const short8*)&es[(16 * wv + n_) * 72 + 32 * kc + quad * 8];
  floatx4 oAcc[2] = {zero4, zero4};
#pragma unroll
  for (int nt = 0; nt < 2; nt++) {
#pragma unroll
    for (int kc = 0; kc < 2; kc++) {
      short8 bv = *(const short8*)&vTs[(16 * nt + n_) * 72 + 32 * kc + quad * 8];
      oAcc[nt] = __builtin_amdgcn_mfma_f32_16x16x32_bf16(ap[kc], bv, oAcc[nt], 0, 0, 0);
    }
  }

  int wy = nw / NWW, wx = nw % NWW;
#pragma unroll
  for (int r = 0; r < 4; r++) {
    int i_r = 16 * wv + 4 * quad + r;
    if (i_r < WS2) {
      int py = i_r / WS_, px = i_r % WS_;
      int hsp = wy * WS_ + py, wsp = wx * WS_ + px;
      size_t o = ((size_t)(b * HH + hsp) * WW + wsp) * HIDDEN + head * HD;
#pragma unroll
      for (int nt = 0; nt < 2; nt++)
        attn_out[o + 16 * nt + n_] = __float2bfloat16(oAcc[nt][r]);
    }
  }
}

// ---------------- Kernel 3: un-shift gather + output projection (MFMA) ----
__global__ __launch_bounds__(256) void proj_mfma_kernel(
    const bf16* __restrict__ attn, const bf16* __restrict__ wfo,
    const float* __restrict__ b_out, float* __restrict__ out) {
  __shared__ bf16 xs[64][112];
  int tid = threadIdx.x;
  int t0 = blockIdx.x * 64;
  int lane = tid & 63, wv = tid >> 6;
  int rowq = lane >> 4, n_ = lane & 15;

  for (int idx = tid; idx < 64 * 12; idx += 256) {
    int tl = idx / 12, seg = idx % 12;
    int tok = t0 + tl;
    int b = tok / (HH * WW); int rem = tok % (HH * WW);
    int h = rem / WW, w = rem % WW;
    int hs = (h - DISP + HH) % HH, wsp = (w - DISP + WW) % WW;
    uint4 u = *(const uint4*)&attn[((size_t)(b * HH + hs) * WW + wsp) * HIDDEN + seg * 8];
    *(uint4*)&xs[tl][seg * 8] = u;
  }
  __syncthreads();

  int kq = rowq * 8;
  short8 afrag[3];
  {
    int m = 16 * wv + n_;
#pragma unroll
    for (int kb = 0; kb < 3; kb++)
      afrag[kb] = *(const short8*)&xs[m][kb * 32 + kq];
  }

  const short8* wf = (const short8*)wfo;
#pragma unroll
  for (int c6 = 0; c6 < 6; c6++) {
    float bias = b_out[c6 * 16 + n_];
    floatx4 acc = (floatx4){bias, bias, bias, bias};
#pragma unroll
    for (int kb = 0; kb < 3; kb++) {
      short8 bfrag = wf[(size_t)((c6 * 3 + kb) * 64 + lane)];
      acc = __builtin_amdgcn_mfma_f32_16x16x32_bf16(afrag[kb], bfrag, acc, 0, 0, 0);
    }
#pragma unroll
    for (int r = 0; r < 4; r++)
      out[(size_t)(t0 + 16 * wv + 4 * rowq + r) * HIDDEN + c6 * 16 + n_] = acc[r];
  }
}

extern "C" void kernel_launch(void* const* d_in, const int* in_sizes, int n_in,
                              void* d_out, int out_size, void* d_ws, size_t ws_size,
                              hipStream_t stream) {
  const float* x     = (const float*)d_in[0];
  const float* w_qkv = (const float*)d_in[1];
  const float* b_qkv = (const float*)d_in[2];
  const float* pos   = (const float*)d_in[3];
  const float* w_out = (const float*)d_in[4];
  const float* b_out = (const float*)d_in[5];
  float* out = (float*)d_out;

  bf16* qb = (bf16*)d_ws;
  bf16* kb = qb + QKV_ELEMS;
  bf16* vb = kb + QKV_ELEMS;
  bf16* ab = vb + QKV_ELEMS;
  bf16* wfq = ab + QKV_ELEMS;              // 27648 bf16
  bf16* wfo = wfq + (size_t)NFRAG_QKV * 8; // 9216 bf16

  prep_weights_kernel<<<18, 256, 0, stream>>>(w_qkv, w_out, wfq, wfo);
  qkv_mfma_kernel<<<TOKENS / 64, 256, 0, stream>>>(x, wfq, b_qkv, qb, kb, vb);
  attn_kernel<<<B_ * HEADS * NW, 256, 0, stream>>>(qb, kb, vb, pos, ab);
  proj_mfma_kernel<<<TOKENS / 64, 256, 0, stream>>>(ab, wfo, b_out, out);
}